// Round 6
// baseline (520.186 us; speedup 1.0000x reference)
//
#include <hip/hip_runtime.h>
#include <hip/hip_bf16.h>

// TreeLoss: hierarchical softmax-style loss over a fixed 2-level tree.
// States: 1 empty + 24 coarse-only + 1000 (coarse,fine) pairs.
// z = 1 + sum_c e_c + sum_{n>=24} e_{n%24} * e_n
// marginal(label<24=c)  = e_c * (1 + sum_{n≡c (24), n>=24} e_n)
// marginal(label>=24)   = e_{label%24} * e_label
// out = mean(log z - log marginal)
//
// R1: two-stage reduction replaced 8192 same-address atomics (−68 us).
// R2: VALU-stripped loop — NEUTRAL: not VALU-bound. Best total (189.6).
// R3: persistent 16-waves/CU pipelined — REGRESSED (+6): occupancy cut.
// R4: max-MLP 2 rows/wave, zero-LDS — NEUTRAL (+4 vs R2).
//     R2/R3/R4 within ±3% despite radically different structures ⇒ the
//     partial kernel is memory-bound (fs half L3-resident per R0 FETCH) and
//     the rest is dispatch overhead. ~144 us of reported dur is fixed
//     harness restore/poison (512 MiB ws fill at ~77 us tops every profile).
// R5: revert to R2's partial shape (best measured) and FUSE the reduction:
//     per-block loss -> relaxed float atomicAdd into 1 of 64 line-padded
//     slots (staggered arrival, no tail) + ACQ_REL slot counter; slot
//     completer forwards to master; master completer writes out. Kills the
//     reduce dispatch, its gap, and the 64 KiB partials round-trip. Tiny
//     8.3 KiB memset zeroes the slot region (ws is 0xAA-poisoned each call).

constexpr int N_COARSE = 24;
constexpr int TOTAL = 1024;      // columns per row
constexpr int BATCH = 32768;
constexpr int WAVES_PER_BLOCK = 4;   // 256 threads
constexpr int GRID1 = BATCH / WAVES_PER_BLOCK;  // 8192 blocks
constexpr int NSLOT = 64;            // 128 blocks per slot
constexpr int SLOT_STRIDE = 16;      // floats; one 64B line per slot

// ws layout (floats): [0..1023] slot sums (stride 16), [1024..2047] slot
// counters (stride 16), [2048] master sum, [2064] master counter.
constexpr int WS_SLOTF = 0;
constexpr int WS_SLOTC = 1024;
constexpr int WS_MSUM  = 2048;
constexpr int WS_MCNT  = 2064;
constexpr int WS_ZERO_BYTES = (2048 + 32) * 4;  // 8320 B

__global__ __launch_bounds__(256) void treeloss_fused(
    const float* __restrict__ fs, const int* __restrict__ labels,
    float* __restrict__ ws, float* __restrict__ out) {
  const int wave = threadIdx.x >> 6;
  const int lane = threadIdx.x & 63;
  const int b = blockIdx.x * WAVES_PER_BLOCK + wave;

  __shared__ float sc48[WAVES_PER_BLOCK][48];  // coarse exps, replicated x2
  __shared__ float blocksum[WAVES_PER_BLOCK];

  const float* __restrict__ row = fs + (size_t)b * TOTAL;
  const float4* __restrict__ row4 = reinterpret_cast<const float4*>(row);
  const int label = labels[b];

  // Issue the whole row up-front: 4x float4 per lane, fully coalesced.
  const float4 v0 = row4[lane];
  const float4 v1 = row4[lane + 64];
  const float4 v2 = row4[lane + 128];
  const float4 v3 = row4[lane + 192];

  // Coarse exp table, replicated so indices never need a mod/wrap.
  if (lane < N_COARSE) {
    const float e = __expf(row[lane]);
    sc48[wave][lane] = e;
    sc48[wave][lane + N_COARSE] = e;
  }
  __syncthreads();

  const int cbase = (lane * 4) % N_COARSE;  // {0,4,...,20}
  float zp = 0.0f;  // partial of (z - 1)

  // j = 0: columns n = 4*lane + k; n < 24 (lanes 0..5) are coarse-only.
  {
    const float vv[4] = {v0.x, v0.y, v0.z, v0.w};
#pragma unroll
    for (int k = 0; k < 4; ++k) {
      const int n = lane * 4 + k;
      const float en = __expf(vv[k]);
      if (n < N_COARSE) zp += en;
      else zp += sc48[wave][cbase + k] * en;
    }
  }
  // j = 1..3: (j*256) % 24 = 16, 8, 0 — compile-time LDS offsets, idx<=39<48.
  {
    const float vv[4] = {v1.x, v1.y, v1.z, v1.w};
#pragma unroll
    for (int k = 0; k < 4; ++k) zp += sc48[wave][cbase + 16 + k] * __expf(vv[k]);
  }
  {
    const float vv[4] = {v2.x, v2.y, v2.z, v2.w};
#pragma unroll
    for (int k = 0; k < 4; ++k) zp += sc48[wave][cbase + 8 + k] * __expf(vv[k]);
  }
  {
    const float vv[4] = {v3.x, v3.y, v3.z, v3.w};
#pragma unroll
    for (int k = 0; k < 4; ++k) zp += sc48[wave][cbase + k] * __expf(vv[k]);
  }

  // Label gather. For label<24: fine nodes ≡ label (mod 24) are
  // label+24*(lane+1), at most 42 of them; loads are L1-hot (row streamed).
  float g = 0.0f;
  if (label < N_COARSE) {
    const int gi = label + N_COARSE * (lane + 1);
    if (gi < TOTAL) g = __expf(row[gi]);
  }

#pragma unroll
  for (int off = 32; off > 0; off >>= 1) {
    zp += __shfl_xor(zp, off);
    g  += __shfl_xor(g, off);
  }

  if (lane == 0) {
    float m;
    if (label < N_COARSE) m = sc48[wave][label] * (1.0f + g);
    else m = sc48[wave][label % N_COARSE] * __expf(row[label]);
    blocksum[wave] = __logf(1.0f + zp) - __logf(m);
  }
  __syncthreads();

  // ---- fused reduction: block -> slot -> master -> out ----
  if (threadIdx.x == 0) {
    const float bsum = blocksum[0] + blocksum[1] + blocksum[2] + blocksum[3];
    const int slot = blockIdx.x & (NSLOT - 1);
    float* slotf = ws + WS_SLOTF + slot * SLOT_STRIDE;
    unsigned int* slotc =
        reinterpret_cast<unsigned int*>(ws + WS_SLOTC) + slot * SLOT_STRIDE;

    const float fold = __hip_atomic_fetch_add(
        slotf, bsum, __ATOMIC_RELAXED, __HIP_MEMORY_SCOPE_AGENT);
    const unsigned int cold = __hip_atomic_fetch_add(
        slotc, 1u, __ATOMIC_ACQ_REL, __HIP_MEMORY_SCOPE_AGENT);

    if (cold == (GRID1 / NSLOT) - 1) {  // this block completed its slot
      const float slot_total = fold + bsum;
      float* msum = ws + WS_MSUM;
      unsigned int* mcnt = reinterpret_cast<unsigned int*>(ws + WS_MCNT);
      __hip_atomic_fetch_add(msum, slot_total, __ATOMIC_RELAXED,
                             __HIP_MEMORY_SCOPE_AGENT);
      const unsigned int mold = __hip_atomic_fetch_add(
          mcnt, 1u, __ATOMIC_ACQ_REL, __HIP_MEMORY_SCOPE_AGENT);
      if (mold == NSLOT - 1) {  // all slots folded: publish the mean
        const float total = __hip_atomic_load(msum, __ATOMIC_ACQUIRE,
                                              __HIP_MEMORY_SCOPE_AGENT);
        out[0] = total * (1.0f / (float)BATCH);
      }
    }
  }
}

extern "C" void kernel_launch(void* const* d_in, const int* in_sizes, int n_in,
                              void* d_out, int out_size, void* d_ws, size_t ws_size,
                              hipStream_t stream) {
  const float* fs = (const float*)d_in[0];
  const int* labels = (const int*)d_in[1];
  // d_in[2] (stateSpace) is deterministic structure; hardcoded in the kernel.
  float* out = (float*)d_out;
  float* ws = (float*)d_ws;

  hipMemsetAsync(ws, 0, WS_ZERO_BYTES, stream);  // ws is 0xAA-poisoned each call
  treeloss_fused<<<GRID1, 256, 0, stream>>>(fs, labels, ws, out);
}

// Round 7
// 190.101 us; speedup vs baseline: 2.7364x; 2.7364x over previous
//
#include <hip/hip_runtime.h>
#include <hip/hip_bf16.h>

// TreeLoss: hierarchical softmax-style loss over a fixed 2-level tree.
// States: 1 empty + 24 coarse-only + 1000 (coarse,fine) pairs.
// z = 1 + sum_c e_c + sum_{n>=24} e_{n%24} * e_n
// marginal(label<24=c)  = e_c * (1 + sum_{n≡c (24), n>=24} e_n)
// marginal(label>=24)   = e_{label%24} * e_label
// out = mean(log z - log marginal)
//
// R1: two-stage reduction replaced 8192 same-address atomics (−68 us).
// R2: VALU-stripped loop — best measured total (189.6 us).
// R3: persistent 16-waves/CU pipelined — REGRESSED (+6): occupancy cut.
// R4: max-MLP 2 rows/wave, zero-LDS — NEUTRAL (+4 vs R2).
// R5: fused reduction via agent-scope ACQ_REL atomics — DISASTER (520 us):
//     ~16k ordered RMWs serialize at ~23 ns each on the non-coherent-L2
//     hierarchy. Lesson: a second 4-us dispatch beats ordered atomics 10x.
// R6: REVERT to R2 verbatim. Evidence across R0-R5: controllable time
//     (~46 us = total − ~144 us fixed harness poison/restore, the 512 MiB
//     ws fills at ~77 us top every profile) is the memory-system floor for
//     streaming 128 MiB of half-L3-resident fs + two dispatch overheads.
//     Structure changes of every kind (VALU stripping, persistence, MLP,
//     atomic fusion) were neutral or regressive.

constexpr int N_COARSE = 24;
constexpr int TOTAL = 1024;      // columns per row
constexpr int BATCH = 32768;
constexpr int WAVES_PER_BLOCK = 4;   // 256 threads
constexpr int GRID1 = BATCH / WAVES_PER_BLOCK;  // 8192 blocks, one partial each

__global__ __launch_bounds__(256) void treeloss_partial(
    const float* __restrict__ fs, const int* __restrict__ labels,
    float* __restrict__ partials) {
  const int wave = threadIdx.x >> 6;
  const int lane = threadIdx.x & 63;
  const int b = blockIdx.x * WAVES_PER_BLOCK + wave;  // BATCH % 4 == 0

  __shared__ float sc48[WAVES_PER_BLOCK][48];  // coarse exps, replicated x2
  __shared__ float blocksum[WAVES_PER_BLOCK];

  const float* __restrict__ row = fs + (size_t)b * TOTAL;
  const float4* __restrict__ row4 = reinterpret_cast<const float4*>(row);
  const int label = labels[b];

  // Issue the whole row up-front: 4x float4 per lane, fully coalesced.
  const float4 v0 = row4[lane];
  const float4 v1 = row4[lane + 64];
  const float4 v2 = row4[lane + 128];
  const float4 v3 = row4[lane + 192];

  // Coarse exp table, replicated so indices never need a mod/wrap.
  if (lane < N_COARSE) {
    const float e = __expf(row[lane]);
    sc48[wave][lane] = e;
    sc48[wave][lane + N_COARSE] = e;
  }
  __syncthreads();

  const int cbase = (lane * 4) % N_COARSE;  // one-time magic-mul, in {0,4,..,20}
  float zp = 0.0f;  // partial of (z - 1)

  // j = 0: columns n = 4*lane + k; n < 24 are coarse-only states.
  {
    const float vv[4] = {v0.x, v0.y, v0.z, v0.w};
#pragma unroll
    for (int k = 0; k < 4; ++k) {
      const int n = lane * 4 + k;
      const float en = __expf(vv[k]);
      if (n < N_COARSE) zp += en;                       // lanes 0..5 only
      else zp += sc48[wave][cbase + k] * en;            // c = cbase+k <= 23
    }
  }
  // j = 1..3: K = (j*256) % 24 is a compile-time constant (16, 8, 0).
  {
    const float vv[4] = {v1.x, v1.y, v1.z, v1.w};
#pragma unroll
    for (int k = 0; k < 4; ++k)
      zp += sc48[wave][cbase + 16 + k] * __expf(vv[k]);  // idx <= 39 < 48
  }
  {
    const float vv[4] = {v2.x, v2.y, v2.z, v2.w};
#pragma unroll
    for (int k = 0; k < 4; ++k)
      zp += sc48[wave][cbase + 8 + k] * __expf(vv[k]);
  }
  {
    const float vv[4] = {v3.x, v3.y, v3.z, v3.w};
#pragma unroll
    for (int k = 0; k < 4; ++k)
      zp += sc48[wave][cbase + k] * __expf(vv[k]);
  }

  // Label gather (out of the hot loop). For label<24: fine nodes ≡ label mod 24
  // are label+24*(lane+1), at most 42 of them; loads are L1/L2-hot.
  float g = 0.0f;
  if (label < N_COARSE) {
    const int idx = label + N_COARSE * (lane + 1);
    if (idx < TOTAL) g = __expf(row[idx]);
  }

  // Wave-wide butterfly reduce (64 lanes).
#pragma unroll
  for (int off = 32; off > 0; off >>= 1) {
    zp += __shfl_down(zp, off);
    g += __shfl_down(g, off);
  }

  if (lane == 0) {
    float m;
    if (label < N_COARSE) m = sc48[wave][label] * (1.0f + g);
    else m = sc48[wave][label % N_COARSE] * __expf(row[label]);
    blocksum[wave] = __logf(1.0f + zp) - __logf(m);
  }
  __syncthreads();

  if (threadIdx.x == 0) {
    partials[blockIdx.x] = blocksum[0] + blocksum[1] + blocksum[2] + blocksum[3];
  }
}

__global__ __launch_bounds__(1024) void treeloss_reduce(
    const float* __restrict__ partials, float* __restrict__ out) {
  const int tid = threadIdx.x;
  const int lane = tid & 63;
  const int wave = tid >> 6;
  const float4* __restrict__ p4 = reinterpret_cast<const float4*>(partials);
  const float4 a = p4[tid];           // 8192 floats = 2048 float4
  const float4 c = p4[tid + 1024];
  float s = (a.x + a.y + a.z + a.w) + (c.x + c.y + c.z + c.w);
#pragma unroll
  for (int off = 32; off > 0; off >>= 1) s += __shfl_down(s, off);
  __shared__ float ps[16];
  if (lane == 0) ps[wave] = s;
  __syncthreads();
  if (tid == 0) {
    float t = 0.0f;
#pragma unroll
    for (int w = 0; w < 16; ++w) t += ps[w];
    out[0] = t * (1.0f / (float)BATCH);
  }
}

extern "C" void kernel_launch(void* const* d_in, const int* in_sizes, int n_in,
                              void* d_out, int out_size, void* d_ws, size_t ws_size,
                              hipStream_t stream) {
  const float* fs = (const float*)d_in[0];
  const int* labels = (const int*)d_in[1];
  // d_in[2] (stateSpace) is deterministic structure; hardcoded in the kernel.
  float* out = (float*)d_out;
  float* partials = (float*)d_ws;  // 8192 floats = 32 KiB scratch

  treeloss_partial<<<GRID1, 256, 0, stream>>>(fs, labels, partials);
  treeloss_reduce<<<1, 1024, 0, stream>>>(partials, out);
}